// Round 6
// baseline (29.616 us; speedup 1.0000x reference)
//
#include <hip/hip_runtime.h>

#define NJ 32
#define BLK 256
#define GRAVZ 9.81f

// SoA per-joint constants in ws[k*NJ + j]:
// k: 0=m*cx 1=m*cy 2=m*cz 3=Ibar[2][2] 4=m 5=px 6=py 7=damping
__global__ void precomp_kernel(const float* __restrict__ mass,
                               const float* __restrict__ com,
                               const float* __restrict__ inertia,
                               const float* __restrict__ trans,
                               const float* __restrict__ damping,
                               float* __restrict__ ws)
{
    int j = threadIdx.x;
    if (j >= NJ) return;
    float m  = mass[j];
    float cx = com[3*j+0], cy = com[3*j+1], cz = com[3*j+2];
    float cc = cx*cx + cy*cy + cz*cz;
    ws[0*NJ+j] = m*cx;
    ws[1*NJ+j] = m*cy;
    ws[2*NJ+j] = m*cz;
    ws[3*NJ+j] = inertia[9*j+8] + m*(cc - cz*cz);   // Ibar zz
    ws[4*NJ+j] = m;
    ws[5*NJ+j] = trans[3*j+0];
    ws[6*NJ+j] = trans[3*j+1];
    ws[7*NJ+j] = damping[j];
}

// Inclusive prefix sum over each 32-lane half-wave (Hillis-Steele).
__device__ __forceinline__ float scan32(float x, int lane) {
    #pragma unroll
    for (int d = 1; d < 32; d <<= 1) {
        float t = __shfl_up(x, d, 32);
        if (lane >= d) x += t;
    }
    return x;
}
// Reverse (suffix) inclusive sum over each 32-lane half-wave.
__device__ __forceinline__ float rscan32(float x, int lane) {
    #pragma unroll
    for (int d = 1; d < 32; d <<= 1) {
        float t = __shfl_down(x, d, 32);
        if (lane < 32 - d) x += t;
    }
    return x;
}

__global__ __launch_bounds__(BLK) void rnea_kernel(
    const float* __restrict__ q,
    const float* __restrict__ qd,
    const float* __restrict__ qdd,
    const float* __restrict__ pre,
    float* __restrict__ out,
    int Bn)
{
    const int t    = blockIdx.x * BLK + threadIdx.x;
    const int lane = threadIdx.x & 31;          // joint index
    const int row  = t >> 5;                    // batch row
    if (row >= Bn) return;
    const size_t idx = (size_t)row * NJ + lane; // fully coalesced

    // Per-joint inputs (lane j <-> joint j).
    float qj   = q  [idx];
    float qdj  = qd [idx];
    float qddj = qdd[idx];

    // Per-joint constants, SoA -> one 128B line per 32-lane group (L1-hot).
    float mcx  = pre[0*NJ+lane];
    float mcy  = pre[1*NJ+lane];
    float mcz  = pre[2*NJ+lane];
    float i2z  = pre[3*NJ+lane];
    float m    = pre[4*NJ+lane];
    float px   = pre[5*NJ+lane];
    float py   = pre[6*NJ+lane];
    float damp = pre[7*NJ+lane];

    // ---- Forward pass as prefix sums (world frame). ----
    float phi = scan32(qj,   lane);             // phi_j  = sum_{k<=j} q_k
    float wI  = scan32(qdj,  lane);             // w_j
    float aI  = scan32(qddj, lane);             // alpha_j
    float wP  = wI - qdj;                       // w_{j-1}
    float aP  = aI - qddj;                      // alpha_{j-1}

    float c, s;
    __sincosf(phi, &s, &c);                     // (cos,sin) phi_j
    float cp = __shfl_up(c, 1, 32);             // phi_{j-1}
    float sp = __shfl_up(s, 1, 32);
    if (lane == 0) { cp = 1.f; sp = 0.f; }

    // d_j = Rz(phi_{j-1}) * p_j   (x,y only)
    float dx = cp*px - sp*py;
    float dy = sp*px + cp*py;

    // VL_j = sum_{k<=j} w_{k-1} * (-dy_k, dx_k)
    float VLx = scan32(-wP*dy, lane);
    float VLy = scan32( wP*dx, lane);

    // AL_j = sum_{k<=j} [ alpha_{k-1}*(-dy,dx) + qd_k*(VLy_k, -VLx_k) ]
    float ALx = scan32(fmaf(-aP, dy,  qdj*VLy), lane);
    float ALy = scan32(fmaf( aP, dx, -qdj*VLx), lane);

    // ---- Backward pass as suffix sums (world frame; z-chain only). ----
    // Rotate mc into world frame at phi_j.
    float mcwx = c*mcx - s*mcy;
    float mcwy = s*mcx + c*mcy;

    // fv_l = m*VL + mc_w x (0,0,w)
    float fv_lx = fmaf(m, VLx,  wI*mcwy);
    float fv_ly = fmaf(m, VLy, -wI*mcwx);

    // local force terms: fa_l + (0,0,w) x fv_l   (x,y)
    float llx = fmaf(m, ALx, fmaf(aI, mcwy, -wI*fv_ly));
    float lly = fmaf(m, ALy, fmaf(-aI, mcwx,  wI*fv_lx));

    // F_j = suffix sum of local terms (no rotation between links in world frame)
    float Fx = rscan32(llx, lane);
    float Fy = rscan32(lly, lane);

    // z-moment chain: a_k = fa_az + (VL x fv_l)z ; b_k = (d x F)z
    float a = fmaf(aI, i2z, mcwx*ALy - mcwy*ALx + VLx*fv_ly - VLy*fv_lx);
    float b = dx*Fy - dy*Fx;
    float R = rscan32(a + b, lane);             // GAz_j chain
    float Nz = R - b;

    out[idx] = fmaf(damp, qdj, Nz);             // tau, fully coalesced
}

extern "C" void kernel_launch(void* const* d_in, const int* in_sizes, int n_in,
                              void* d_out, int out_size, void* d_ws, size_t ws_size,
                              hipStream_t stream) {
    const float* q       = (const float*)d_in[0];
    const float* qd      = (const float*)d_in[1];
    const float* qdd     = (const float*)d_in[2];
    const float* trans   = (const float*)d_in[3];
    const float* mass    = (const float*)d_in[4];
    const float* com     = (const float*)d_in[5];
    const float* inertia = (const float*)d_in[6];
    const float* damping = (const float*)d_in[7];
    float* out = (float*)d_out;
    float* pre = (float*)d_ws;   // 8*32 floats = 1 KiB

    hipLaunchKernelGGL(precomp_kernel, dim3(1), dim3(64), 0, stream,
                       mass, com, inertia, trans, damping, pre);

    int Bn = in_sizes[0] / NJ;
    long long threads = (long long)Bn * 32;
    int grid = (int)((threads + BLK - 1) / BLK);
    hipLaunchKernelGGL(rnea_kernel, dim3(grid), dim3(BLK), 0, stream,
                       q, qd, qdd, pre, out, Bn);
}

// Round 7
// 15.523 us; speedup vs baseline: 1.9079x; 1.9079x over previous
//
#include <hip/hip_runtime.h>

#define NJ 32
#define BLK 256

// ---- DPP-based segmented (32-lane) inclusive prefix scan ----
// LLVM AMDGPUAtomicOptimizer pattern, stopped before row_bcast:31 so the
// two 32-lane halves of the wave64 scan independently. All full-rate VALU.
template<int CTRL, int ROW, int BANK>
__device__ __forceinline__ float dpp0(float x) {
    return __int_as_float(
        __builtin_amdgcn_update_dpp(0, __float_as_int(x), CTRL, ROW, BANK, false));
}

__device__ __forceinline__ float scan32(float x) {
    x += dpp0<0x111, 0xf, 0xf>(x);   // row_shr:1
    x += dpp0<0x112, 0xf, 0xf>(x);   // row_shr:2
    x += dpp0<0x114, 0xf, 0xe>(x);   // row_shr:4
    x += dpp0<0x118, 0xf, 0xc>(x);   // row_shr:8
    x += dpp0<0x142, 0xa, 0xf>(x);   // row_bcast:15 -> rows 1,3 (stitch 16-rows)
    return x;
}

// Broadcast lane 31 of each 32-lane group to all its lanes.
// ds_swizzle BitMode: lane' = ((lane & 0) | 31) = 31; offset = 31<<5 = 0x3E0.
__device__ __forceinline__ float bcast31(float x) {
    return __int_as_float(
        __builtin_amdgcn_ds_swizzle(__float_as_int(x), 0x03E0));
}

__global__ __launch_bounds__(BLK) void rnea_kernel(
    const float* __restrict__ q,
    const float* __restrict__ qd,
    const float* __restrict__ qdd,
    const float* __restrict__ trans,
    const float* __restrict__ mass,
    const float* __restrict__ com,
    const float* __restrict__ inertia,
    const float* __restrict__ damping,
    float* __restrict__ out,
    int Bn)
{
    const int t    = blockIdx.x * BLK + threadIdx.x;
    const int lane = threadIdx.x & 31;          // joint index
    const int row  = t >> 5;                    // batch row
    if (row >= Bn) return;
    const size_t idx = (size_t)row * NJ + lane; // fully coalesced

    // Per-joint inputs (lane j <-> joint j).
    float qj   = q  [idx];
    float qdj  = qd [idx];
    float qddj = qdd[idx];

    // Per-joint constants, computed in-lane from the (L1-hot) raw inputs.
    // Only what the z-torque chain needs: mc_xy, Ibar_zz, m, p_xy, damping.
    // (mc_z, p_z and gravity provably never reach tau for a z-revolute chain.)
    float m    = mass[lane];
    float cx   = com[3*lane+0], cy = com[3*lane+1];
    float mcx  = m*cx, mcy = m*cy;
    float i2z  = fmaf(m, cx*cx + cy*cy, inertia[9*lane+8]);   // Ibar_zz
    float px   = trans[3*lane+0], py = trans[3*lane+1];
    float damp = damping[lane];

    // ---- Forward pass as prefix sums (world frame). ----
    float phi = scan32(qj);                     // phi_j
    float wI  = scan32(qdj);                    // w_j
    float aI  = scan32(qddj);                   // alpha_j
    float wP  = wI - qdj;                       // w_{j-1}
    float aP  = aI - qddj;                      // alpha_{j-1}

    float c, s, cp, sp;
    __sincosf(phi, &s, &c);                     // at phi_j
    __sincosf(phi - qj, &sp, &cp);              // at phi_{j-1}

    // d_j = Rz(phi_{j-1}) * p_j   (x,y only)
    float dx = cp*px - sp*py;
    float dy = sp*px + cp*py;

    // VL_j = sum_{k<=j} w_{k-1} * (-dy_k, dx_k)
    float VLx = scan32(-wP*dy);
    float VLy = scan32( wP*dx);

    // AL_j = sum_{k<=j} [ alpha_{k-1}*(-dy,dx) + qd_k*(VLy_k, -VLx_k) ]
    float ALx = scan32(fmaf(-aP, dy,  qdj*VLy));
    float ALy = scan32(fmaf( aP, dx, -qdj*VLx));

    // ---- Backward pass as suffix sums (world frame; z-chain only). ----
    float mcwx = c*mcx - s*mcy;                 // Rz(phi_j) * mc
    float mcwy = s*mcx + c*mcy;

    // fv_l = m*VL + mc_w x (0,0,w)
    float fv_lx = fmaf(m, VLx,  wI*mcwy);
    float fv_ly = fmaf(m, VLy, -wI*mcwx);

    // local force terms: fa_l + (0,0,w) x fv_l   (x,y)
    float llx = fmaf(m, ALx, fmaf( aI, mcwy, -wI*fv_ly));
    float lly = fmaf(m, ALy, fmaf(-aI, mcwx,  wI*fv_lx));

    // F_j = suffix sum: S = T - P + x  (T = segment total via lane-31 bcast)
    float Px = scan32(llx);
    float Py = scan32(lly);
    float Fx = bcast31(Px) - Px + llx;
    float Fy = bcast31(Py) - Py + lly;

    // z-moment chain: a_k = fa_az + (VL x fv_l)z ; b_k = (d x F)z
    float a = fmaf(aI, i2z, mcwx*ALy - mcwy*ALx + VLx*fv_ly - VLy*fv_lx);
    float b = dx*Fy - dy*Fx;
    float ab = a + b;
    float Pr = scan32(ab);
    float Nz = bcast31(Pr) - Pr + ab - b;       // suffix(a+b) - b

    out[idx] = fmaf(damp, qdj, Nz);             // tau, fully coalesced
}

extern "C" void kernel_launch(void* const* d_in, const int* in_sizes, int n_in,
                              void* d_out, int out_size, void* d_ws, size_t ws_size,
                              hipStream_t stream) {
    const float* q       = (const float*)d_in[0];
    const float* qd      = (const float*)d_in[1];
    const float* qdd     = (const float*)d_in[2];
    const float* trans   = (const float*)d_in[3];
    const float* mass    = (const float*)d_in[4];
    const float* com     = (const float*)d_in[5];
    const float* inertia = (const float*)d_in[6];
    const float* damping = (const float*)d_in[7];
    float* out = (float*)d_out;

    int Bn = in_sizes[0] / NJ;
    long long threads = (long long)Bn * 32;
    int grid = (int)((threads + BLK - 1) / BLK);
    hipLaunchKernelGGL(rnea_kernel, dim3(grid), dim3(BLK), 0, stream,
                       q, qd, qdd, trans, mass, com, inertia, damping, out, Bn);
}